// Round 8
// baseline (17019.221 us; speedup 1.0000x reference)
//
#include <hip/hip_runtime.h>
#include <stdint.h>
#include <stddef.h>

// ACT-LSTM, B=32 T=512 IN=50 H=512 OUT=66, MAX_PONDER=10, EPS=0.01, fp32.
// Round 8: two structural changes on R7:
//  (1) Tree barrier -> direct producer/consumer FLAGS: each block stores
//      flag[bid]=ph+1 after vmcnt-draining its LLC h2 stores; consumers poll
//      all 128 flags (dwordx2/lane + ballot) then stage. 1 LLC RT instead of 3.
//  (2) k-sliced GEMM: thread = (batch=tid&31, k-slice=tid>>5) covers 16 cols
//      x 64 k -> 16 ds_read_b128 (was 128; 8x less LDS pipe, conflict-free
//      address set), weights repacked k-major [k][2048] (wave reads 2 distinct
//      64B lines/k, L1-broadcast). Partials reduced via padded LDS in the same
//      region as the ACT decision (no extra syncs).

#define NBLK 128

// ---------------- ws layout (float offsets) ----------------
// wh   : [0, 8388608)            512*32*512  (32 MB)
// hbuf : [8388608, 8421376)      2*16384     h ping-pong (packed [k4][b*4+kl])
// bar  : [8421376, 8421888)      512 uints   flags[128] + pad
// W_kb : [8421888, 9470464)      1048576     W_hh repacked [k][2048] col=bid*16+c
// W_iT : [9470464, 9574912)      51*2048     W_ih repacked [k][j*4+g]
// W_oT : [9574912, 9608704)      512*66      W_out transposed [k][o]
#define WS_NEED_BYTES 38434816ull

__device__ __forceinline__ float sigmf(float v) { return 1.0f / (1.0f + expf(-v)); }

// LLC-coherent (cross-XCD) store: bypass L1+L2 (sc0 sc1).
__device__ __forceinline__ void store_llc(float* p, float v) {
  asm volatile("global_store_dword %0, %1, off sc0 sc1" :: "v"(p), "v"(v) : "memory");
}
__device__ __forceinline__ void store_llc_u(unsigned* p, unsigned v) {
  asm volatile("global_store_dword %0, %1, off sc0 sc1" :: "v"(p), "v"(v) : "memory");
}

#if defined(__has_builtin)
#if __has_builtin(__builtin_amdgcn_global_load_lds)
#define HAVE_GLLDS 1
#endif
#endif

// LLC-coherent global->LDS DMA, 16 B/lane. aux=0x11 = SC0|SC1.
__device__ __forceinline__ void stage_instr(const float* gp, float* lp) {
#ifdef HAVE_GLLDS
  __builtin_amdgcn_global_load_lds((const __attribute__((address_space(1))) unsigned int*)gp,
                                   (__attribute__((address_space(3))) unsigned int*)lp,
                                   16, 0, 0x11);
#else
  float4 tmp;
  asm volatile("global_load_dwordx4 %0, %1, off sc0 sc1" : "=v"(tmp) : "v"(gp) : "memory");
  asm volatile("s_waitcnt vmcnt(0)" ::: "memory");
  *(float4*)(lp + (threadIdx.x & 63) * 4) = tmp;
#endif
}

// ------------------------------------------------------------------
// prep: repack weights + zero flags.
// W_kb[k*2048 + C] = W_hh[(g*512 + j)*512 + k], g=(C>>2)&3, j=4*(C>>4)+(C&3).
__global__ void prep_k(const float* __restrict__ W_ih, const float* __restrict__ W_hh,
                       const float* __restrict__ W_out,
                       float* __restrict__ W_kb, float* __restrict__ W_iT,
                       float* __restrict__ W_oT, unsigned* __restrict__ bar) {
  int idx = blockIdx.x * 256 + threadIdx.x;
  if (idx < 1048576) {
    int C = idx & 2047, k = idx >> 11;
    int g = (C >> 2) & 3, j = 4 * (C >> 4) + (C & 3);
    W_kb[idx] = W_hh[(size_t)(g * 512 + j) * 512 + k];
  }
  int i2 = idx - 1048576;
  if (i2 >= 0 && i2 < 104448) {
    int col = i2 & 2047, k = i2 >> 11;
    int g = col & 3, j = col >> 2;
    W_iT[i2] = W_ih[(size_t)((g << 9) + j) * 51 + k];
  }
  int i3 = idx - 1153024;
  if (i3 >= 0 && i3 < 33792) {
    int k = i3 / 66, o = i3 - k * 66;
    W_oT[i3] = W_out[(size_t)o * 512 + k];
  }
  int i4 = idx - 1186816;
  if (i4 >= 0 && i4 < 512) bar[i4] = 0u;
}

// ------------------------------------------------------------------
// persistent ACT-LSTM: 128 blocks x 256 threads.
// Block owns 16 cols: c -> (gate g=c>>2, j = 4*bid + (c&3)).
// GEMM threads: (b_g = tid&31, s = tid>>5): 16 cols x k in [64s,64s+64).
// Owner thread (b_i=tid>>3, sub=tid&7, sub<4) owns (b_i, j=4bid+sub).
__global__ void __launch_bounds__(256)
act_main(const float* __restrict__ x, const float* __restrict__ bvec,
         const float* __restrict__ W_halt, const float* __restrict__ b_halt,
         const float* __restrict__ W_kb, const float* __restrict__ W_iT,
         float* __restrict__ hbuf, unsigned* __restrict__ bar,
         float* __restrict__ wh, float* __restrict__ p_out) {
  __shared__ float hch[16384];       // staged h2, 64 KB (packed [k4][b*4+kl])
  __shared__ float pacc[16 * 292];   // GEMM partials [c][s*36+b], padded strides
  __shared__ float xch2[512];        // reduced gate pre-acts [b*16+c]
  __shared__ float hps[256];         // halt partials
  __shared__ float S_cum[32], S_p[32], S_nupd[32], S_rem[32];
  __shared__ int S_flag[1];          // alldone broadcast

  const int tid = threadIdx.x, bid = blockIdx.x;
  const int b_i = tid >> 3, sub = tid & 7;            // owner mapping
  const int b_g = tid & 31, s = tid >> 5;             // GEMM mapping
  const int wid = tid >> 6, lane4 = (tid & 63) * 4;
  const int jown = bid * 4 + sub;                     // owner's j (sub<4)
  const int hoidx = bid * 128 + b_i * 4 + sub;
  const float4* hch4 = (const float4*)hch;
  const float4* Wq = (const float4*)W_halt;

  unsigned* flags = bar;             // flags[128]
  const float bh = b_halt[0];

  // owner constants: flag column + biases for its 4 gates
  float wf0 = 0.f, wf1 = 0.f, wf2 = 0.f, wf3 = 0.f;
  float bs0 = 0.f, bs1 = 0.f, bs2 = 0.f, bs3 = 0.f;
  if (sub < 4) {
    const float4 wf = *(const float4*)(W_iT + 50 * 2048 + jown * 4);
    wf0 = wf.x; wf1 = wf.y; wf2 = wf.z; wf3 = wf.w;
    bs0 = bvec[jown]; bs1 = bvec[512 + jown]; bs2 = bvec[1024 + jown]; bs3 = bvec[1536 + jown];
  }

  // owner state
  float cS = 0.f, hprev = 0.f, acc_h = 0.f, acc_c = 0.f;
  float gA0 = 0.f, gA1 = 0.f, gA2 = 0.f, gA3 = 0.f;           // gAcc (linearity)
  float gc0 = 0.f, gc1 = 0.f, gc2 = 0.f, gc3 = 0.f;           // gx(t)
  float gn0 = 0.f, gn1 = 0.f, gn2 = 0.f, gn3 = 0.f;           // gx(t+1)
  if (sub < 4) {  // x-projection for t=0
    gc0 = bs0; gc1 = bs1; gc2 = bs2; gc3 = bs3;
    const float* xr = x + (size_t)b_i * 512 * 50;
    for (int k = 0; k < 50; ++k) {
      const float xv = xr[k];
      const float4 w = *(const float4*)(W_iT + k * 2048 + jown * 4);
      gc0 = fmaf(xv, w.x, gc0); gc1 = fmaf(xv, w.y, gc1);
      gc2 = fmaf(xv, w.z, gc2); gc3 = fmaf(xv, w.w, gc3);
    }
  }
  if (tid < 32) { S_cum[tid] = 0.f; S_nupd[tid] = 0.f; S_rem[tid] = 0.f; }
  int mydone = 0;
  int t = 0, n = 0, first = 1;
  unsigned ph = 0;
  __syncthreads();

  while (true) {
    if (first) {
      // ---- phase 0: step 0 of t=0 (h=0 -> gemm contribution = 0) ----
      if (sub < 4) {
        const float c_new = sigmf(gc0 + wf0) * tanhf(gc2 + wf2);
        const float h_new = sigmf(gc3 + wf3) * tanhf(c_new);
        store_llc(&hbuf[hoidx], h_new);
        cS = c_new; hprev = h_new;
      }
      n = 0; first = 0;
    } else {
      // ---- poll: all 128 flags >= ph (each wave independently) ----
      {
        const unsigned* fp = flags + ((tid & 63) << 1);
        while (true) {
          unsigned long long fv;
          asm volatile("global_load_dwordx2 %0, %1, off sc0 sc1" : "=v"(fv) : "v"(fp) : "memory");
          asm volatile("s_waitcnt vmcnt(0)" ::: "memory");
          const unsigned lo = (unsigned)fv, hi = (unsigned)(fv >> 32);
          if (__ballot((lo >= ph) && (hi >= ph)) == ~0ull) break;
        }
      }
      // ---- stage h2 (64 KB) from buf[(ph-1)&1]; 16 KB per wave ----
      const float* hin = hbuf + ((ph & 1u) ^ 1u) * 16384;
      {
        const float* gp = hin + wid * 4096 + lane4;
        float* lp = &hch[wid * 4096];
        #pragma unroll
        for (int q = 0; q < 16; ++q) stage_instr(gp + q * 256, lp + q * 256);
      }
      // under the DMA: x-projection for t+1 (once per timestep)
      if (n == 0 && sub < 4) {
        const int tn = (t + 1 > 511) ? 511 : t + 1;
        gn0 = bs0; gn1 = bs1; gn2 = bs2; gn3 = bs3;
        const float* xr = x + ((size_t)b_i * 512 + tn) * 50;
        for (int k = 0; k < 50; ++k) {
          const float xv = xr[k];
          const float4 w = *(const float4*)(W_iT + k * 2048 + jown * 4);
          gn0 = fmaf(xv, w.x, gn0); gn1 = fmaf(xv, w.y, gn1);
          gn2 = fmaf(xv, w.z, gn2); gn3 = fmaf(xv, w.w, gn3);
        }
      }
      asm volatile("s_waitcnt vmcnt(0)" ::: "memory");
      __syncthreads();

      // ---- k-sliced GEMM: 16 cols x 64 k per thread ----
      {
        float acc[16];
        #pragma unroll
        for (int q = 0; q < 16; ++q) acc[q] = 0.f;
        const float* hsl = hch + (s * 16) * 128 + b_g * 4;
        const float* wbase = W_kb + bid * 16 + (size_t)(s * 64) * 2048;
        #pragma unroll 4
        for (int i = 0; i < 16; ++i) {
          const float4 h4 = *(const float4*)(hsl + i * 128);     // conflict-free
          const float* wk = wbase + (size_t)(i * 4) * 2048;
          #pragma unroll
          for (int kl = 0; kl < 4; ++kl) {
            const float hv = (kl == 0) ? h4.x : (kl == 1) ? h4.y : (kl == 2) ? h4.z : h4.w;
            const float4 w0 = *(const float4*)(wk + kl * 2048);
            const float4 w1 = *(const float4*)(wk + kl * 2048 + 4);
            const float4 w2 = *(const float4*)(wk + kl * 2048 + 8);
            const float4 w3 = *(const float4*)(wk + kl * 2048 + 12);
            acc[0]  = fmaf(hv, w0.x, acc[0]);  acc[1]  = fmaf(hv, w0.y, acc[1]);
            acc[2]  = fmaf(hv, w0.z, acc[2]);  acc[3]  = fmaf(hv, w0.w, acc[3]);
            acc[4]  = fmaf(hv, w1.x, acc[4]);  acc[5]  = fmaf(hv, w1.y, acc[5]);
            acc[6]  = fmaf(hv, w1.z, acc[6]);  acc[7]  = fmaf(hv, w1.w, acc[7]);
            acc[8]  = fmaf(hv, w2.x, acc[8]);  acc[9]  = fmaf(hv, w2.y, acc[9]);
            acc[10] = fmaf(hv, w2.z, acc[10]); acc[11] = fmaf(hv, w2.w, acc[11]);
            acc[12] = fmaf(hv, w3.x, acc[12]); acc[13] = fmaf(hv, w3.y, acc[13]);
            acc[14] = fmaf(hv, w3.z, acc[14]); acc[15] = fmaf(hv, w3.w, acc[15]);
          }
        }
        #pragma unroll
        for (int c = 0; c < 16; ++c) pacc[c * 292 + s * 36 + b_g] = acc[c];
      }
      // ---- halt partials (conflict-free contiguous-by-lane) ----
      {
        float hp = 0.f;
        #pragma unroll
        for (int i = 0; i < 16; ++i) {
          const int f = i * 256 + tid;
          const float4 hv = hch4[f];
          const float4 wv = Wq[f >> 5];
          hp = fmaf(hv.x, wv.x, fmaf(hv.y, wv.y, fmaf(hv.z, wv.z, fmaf(hv.w, wv.w, hp))));
        }
        hps[tid] = hp;
      }
      __syncthreads();

      // ---- reduction (all threads) + ACT decision (wave 0) ----
      {
        #pragma unroll
        for (int e = 0; e < 2; ++e) {
          const int f = tid + e * 256;
          const int b = f >> 4, c = f & 15;
          const float* pp = pacc + c * 292 + b;
          float v = 0.f;
          #pragma unroll
          for (int s2 = 0; s2 < 8; ++s2) v += pp[s2 * 36];
          xch2[f] = v;
        }
      }
      if (tid < 64) {
        int vote = 1;
        if (tid < 32) {
          float d = 0.f;
          #pragma unroll
          for (int r = 0; r < 8; ++r) d += hps[tid + 32 * r];
          const float halt = sigmf(d + bh);
          const float cum = S_cum[tid];
          const int done = mydone;
          const int halted = ((cum + halt) > 0.99f) || (n == 9);
          S_p[tid] = done ? 0.f : (halted ? (1.f - cum) : halt);
          S_nupd[tid] += done ? 0.f : 1.f;
          S_rem[tid] += (done || !halted) ? 0.f : (1.f - cum);
          S_cum[tid] = cum + (done ? 0.f : halt);
          mydone = done | halted;
          vote = mydone;
        }
        const unsigned long long bal = __ballot(vote);
        if (tid == 0) S_flag[0] = (bal == ~0ull) ? 1 : 0;
      }
      __syncthreads();
      const int alldone = S_flag[0];

      // ---- owner combine: accumulate + one cell step ----
      float g0 = 0.f, g1 = 0.f, g2 = 0.f, g3 = 0.f, p = 0.f;
      if (sub < 4) {
        const int bb = b_i * 16 + sub;
        g0 = xch2[bb]; g1 = xch2[bb + 4]; g2 = xch2[bb + 8]; g3 = xch2[bb + 12];
        p = S_p[b_i];
        gA0 = fmaf(p, g0, gA0); gA1 = fmaf(p, g1, gA1);
        gA2 = fmaf(p, g2, gA2); gA3 = fmaf(p, g3, gA3);
        acc_h = fmaf(p, hprev, acc_h);
        acc_c = fmaf(p, cS, acc_c);
      }

      if (alldone) {  // timestep t ends; fresh step of t+1 in the same phase
        if (sub < 4)
          wh[(size_t)t * 16384 + (size_t)b_i * 512 + jown] = acc_h;
        if (bid == 0 && tid < 32)
          p_out[(size_t)tid * 512 + t] = S_nupd[tid] + S_rem[tid];
        if (tid < 32) { S_cum[tid] = 0.f; S_nupd[tid] = 0.f; S_rem[tid] = 0.f; }
        mydone = 0;
        t += 1; n = 0;
        if (t == 512) break;        // uniform (deterministic replicated decisions)
        if (sub < 4) {              // fresh gates = gx(t+1) + wf + gAcc (no GEMM)
          const float c_new = sigmf(gn1 + wf1 + gA1) * acc_c +
                              sigmf(gn0 + wf0 + gA0) * tanhf(gn2 + wf2 + gA2);
          const float h_new = sigmf(gn3 + wf3 + gA3) * tanhf(c_new);
          store_llc(&hbuf[(ph & 1u) * 16384 + hoidx], h_new);
          cS = c_new; hprev = h_new;
          acc_h = 0.f; acc_c = 0.f;
          gA0 = 0.f; gA1 = 0.f; gA2 = 0.f; gA3 = 0.f;
          gc0 = gn0; gc1 = gn1; gc2 = gn2; gc3 = gn3;
        }
      } else {        // continue: step n+1 gates = gx(t) + gemm
        if (sub < 4) {
          const float c_new = sigmf(gc1 + g1) * cS + sigmf(gc0 + g0) * tanhf(gc2 + g2);
          const float h_new = sigmf(gc3 + g3) * tanhf(c_new);
          store_llc(&hbuf[(ph & 1u) * 16384 + hoidx], h_new);
          cS = c_new; hprev = h_new;
        }
        n += 1;
      }
    }

    // ---- publish: drain h2 stores, then set this block's flag ----
    asm volatile("s_waitcnt vmcnt(0)" ::: "memory");
    __syncthreads();
    if (tid == 0) store_llc_u(&flags[bid], ph + 1u);
    ph += 1;
  }
}

// ------------------------------------------------------------------
// epilogue: out[b,t,:] = seg-softmax(wh[t,b,:] @ W_out^T + b_out)
__global__ void __launch_bounds__(256)
epi_k(const float* __restrict__ wh, const float* __restrict__ W_oT,
      const float* __restrict__ b_out, float* __restrict__ out) {
  __shared__ float hl[4][512];
  __shared__ float yl[4][66];
  const int tid = threadIdx.x, pair = tid >> 6, lane = tid & 63;
  const int bt = blockIdx.x * 4 + pair;
  const int b = bt >> 9, t = bt & 511;
  const float* hsrc = wh + (size_t)t * 16384 + (size_t)b * 512;
  *(float4*)&hl[pair][lane * 8] = *(const float4*)(hsrc + lane * 8);
  *(float4*)&hl[pair][lane * 8 + 4] = *(const float4*)(hsrc + lane * 8 + 4);
  __syncthreads();
  if (lane < 33) {
    const int o = lane * 2;
    float y0 = b_out[o], y1 = b_out[o + 1];
    const float* hp_ = hl[pair];
    #pragma unroll 8
    for (int k = 0; k < 512; ++k) {
      const float h = hp_[k];
      const float2 w = *(const float2*)(W_oT + k * 66 + o);
      y0 = fmaf(h, w.x, y0);
      y1 = fmaf(h, w.y, y1);
    }
    yl[pair][o] = y0; yl[pair][o + 1] = y1;
  }
  __syncthreads();
  if (tid < 24) {
    const int pr = tid / 6, g = tid - pr * 6;
    const int bt2 = blockIdx.x * 4 + pr;
    const float* yp = &yl[pr][g * 11];
    float m = yp[0];
    for (int u = 1; u < 11; ++u) m = fmaxf(m, yp[u]);
    float e[11], ssum = 0.f;
    for (int u = 0; u < 11; ++u) { e[u] = expf(yp[u] - m); ssum += e[u]; }
    const float inv = 1.0f / ssum;
    float* op = out + (size_t)bt2 * 66 + g * 11;
    for (int u = 0; u < 11; ++u) op[u] = e[u] * inv;
  }
}

// ------------------------------------------------------------------
extern "C" void kernel_launch(void* const* d_in, const int* in_sizes, int n_in,
                              void* d_out, int out_size, void* d_ws, size_t ws_size,
                              hipStream_t stream) {
  (void)in_sizes; (void)n_in; (void)out_size;
  const float* x      = (const float*)d_in[0];
  const float* W_ih   = (const float*)d_in[1];
  const float* W_hh   = (const float*)d_in[2];
  const float* bvec   = (const float*)d_in[3];
  const float* W_out  = (const float*)d_in[4];
  const float* b_out  = (const float*)d_in[5];
  const float* W_halt = (const float*)d_in[6];
  const float* b_halt = (const float*)d_in[7];
  float* out = (float*)d_out;
  float* ws  = (float*)d_ws;

  if (ws_size < (size_t)WS_NEED_BYTES) return;  // visible failure if ws too small

  float* wh     = ws;
  float* hbuf   = ws + 8388608;
  unsigned* bar = (unsigned*)(ws + 8421376);
  float* W_kb   = ws + 8421888;
  float* W_iT   = ws + 9470464;
  float* W_oT   = ws + 9574912;
  float* p_out  = out + 1081344;  // B*T*OUT

  hipLaunchKernelGGL(prep_k, dim3(4638), dim3(256), 0, stream,
                     W_ih, W_hh, W_out, W_kb, W_iT, W_oT, bar);

  void* args[10];
  args[0] = (void*)&x;      args[1] = (void*)&bvec;  args[2] = (void*)&W_halt;
  args[3] = (void*)&b_halt; args[4] = (void*)&W_kb;  args[5] = (void*)&W_iT;
  args[6] = (void*)&hbuf;   args[7] = (void*)&bar;   args[8] = (void*)&wh;
  args[9] = (void*)&p_out;
  hipLaunchCooperativeKernel((void*)act_main, dim3(NBLK), dim3(256), args, 0, stream);

  hipLaunchKernelGGL(epi_k, dim3(4096), dim3(256), 0, stream, wh, W_oT, b_out, out);
}

// Round 9
// 14489.925 us; speedup vs baseline: 1.1746x; 1.1746x over previous
//
#include <hip/hip_runtime.h>
#include <stdint.h>
#include <stddef.h>

// ACT-LSTM, B=32 T=512 IN=50 H=512 OUT=66, MAX_PONDER=10, EPS=0.01, fp32.
// Round 9: R7 linearity structure + fixed R8 ideas:
//  - per-WAVE flag poll: wave w polls only its 32 producer blocks (the exact
//    writers of the 16 KB h-region wave w stages & consumes) -> 4x less LLC
//    poll traffic on disjoint lines, and NO barrier between staging and GEMM
//    (each wave: poll -> DMA -> vmcnt -> GEMM on own region).
//  - k-sliced GEMM (16 ds_read_b128/thread) with PER-BLOCK-CONTIGUOUS weights
//    W_ks[bid][k][16] (32 KB linear slice -> fits L1; R8's 8KB-stride layout
//    thrashed L1's 32KB with a 64KB tag footprint).
// Owner h2 stores sit after sync_c, by which point all 4 waves' polls have
// covered all 128 flags -> ping-pong overwrite remains safe.

#define NBLK 128

// ---------------- ws layout (float offsets) ----------------
// wh   : [0, 8388608)            512*32*512  (32 MB)
// hbuf : [8388608, 8421376)      2*16384     h ping-pong (packed [k4][b*4+kl])
// bar  : [8421376, 8421888)      512 uints   flags[128] (group g = [32g,32g+32))
// W_ks : [8421888, 9470464)      1048576     W_hh repacked [bid][k][16 cols]
// W_iT : [9470464, 9574912)      51*2048     W_ih repacked [k][j*4+g]
// W_oT : [9574912, 9608704)      512*66      W_out transposed [k][o]
#define WS_NEED_BYTES 38434816ull

__device__ __forceinline__ float sigmf(float v) { return 1.0f / (1.0f + expf(-v)); }

// LLC-coherent (cross-XCD) store: bypass L1+L2 (sc0 sc1).
__device__ __forceinline__ void store_llc(float* p, float v) {
  asm volatile("global_store_dword %0, %1, off sc0 sc1" :: "v"(p), "v"(v) : "memory");
}
__device__ __forceinline__ void store_llc_u(unsigned* p, unsigned v) {
  asm volatile("global_store_dword %0, %1, off sc0 sc1" :: "v"(p), "v"(v) : "memory");
}

#if defined(__has_builtin)
#if __has_builtin(__builtin_amdgcn_global_load_lds)
#define HAVE_GLLDS 1
#endif
#endif

// LLC-coherent global->LDS DMA, 16 B/lane. aux=0x11 = SC0|SC1.
__device__ __forceinline__ void stage_instr(const float* gp, float* lp) {
#ifdef HAVE_GLLDS
  __builtin_amdgcn_global_load_lds((const __attribute__((address_space(1))) unsigned int*)gp,
                                   (__attribute__((address_space(3))) unsigned int*)lp,
                                   16, 0, 0x11);
#else
  float4 tmp;
  asm volatile("global_load_dwordx4 %0, %1, off sc0 sc1" : "=v"(tmp) : "v"(gp) : "memory");
  asm volatile("s_waitcnt vmcnt(0)" ::: "memory");
  *(float4*)(lp + (threadIdx.x & 63) * 4) = tmp;
#endif
}

// ------------------------------------------------------------------
// prep: repack weights + zero flags.
// W_ks[bid*8192 + k*16 + c] = W_hh[((c>>2)*512 + 4*bid + (c&3))*512 + k]
__global__ void prep_k(const float* __restrict__ W_ih, const float* __restrict__ W_hh,
                       const float* __restrict__ W_out,
                       float* __restrict__ W_ks, float* __restrict__ W_iT,
                       float* __restrict__ W_oT, unsigned* __restrict__ bar) {
  int idx = blockIdx.x * 256 + threadIdx.x;
  if (idx < 1048576) {
    int c = idx & 15, k = (idx >> 4) & 511, bid = idx >> 13;
    int g = c >> 2, j = 4 * bid + (c & 3);
    W_ks[idx] = W_hh[(size_t)(g * 512 + j) * 512 + k];
  }
  int i2 = idx - 1048576;
  if (i2 >= 0 && i2 < 104448) {
    int col = i2 & 2047, k = i2 >> 11;
    int g = col & 3, j = col >> 2;
    W_iT[i2] = W_ih[(size_t)((g << 9) + j) * 51 + k];
  }
  int i3 = idx - 1153024;
  if (i3 >= 0 && i3 < 33792) {
    int k = i3 / 66, o = i3 - k * 66;
    W_oT[i3] = W_out[(size_t)o * 512 + k];
  }
  int i4 = idx - 1186816;
  if (i4 >= 0 && i4 < 512) bar[i4] = 0u;
}

// ------------------------------------------------------------------
// persistent ACT-LSTM: 128 blocks x 256 threads.
// Block owns 16 cols: c -> (gate g=c>>2, j=4*bid+(c&3)).
// GEMM thread (b_g=tid&31, s=tid>>5): 16 cols x k in [64s,64s+64).
// Wave w stages hbuf region [w*4096,+4096) = k4 [32w,32w+32) = its own slices.
// Owner thread (b_i=tid>>3, sub=tid&7, sub<4) owns (b_i, j=4bid+sub).
__global__ void __launch_bounds__(256)
act_main(const float* __restrict__ x, const float* __restrict__ bvec,
         const float* __restrict__ W_halt, const float* __restrict__ b_halt,
         const float* __restrict__ W_ks, const float* __restrict__ W_iT,
         float* __restrict__ hbuf, unsigned* __restrict__ bar,
         float* __restrict__ wh, float* __restrict__ p_out) {
  __shared__ float hch[16384];       // staged h2, 64 KB (packed [k4][b*4+kl])
  __shared__ float pacc[16 * 292];   // GEMM partials [c][s*36+b], padded strides
  __shared__ float xch2[512];        // reduced gate pre-acts [b*16+c]
  __shared__ float hps[256];         // halt partials
  __shared__ float S_cum[32], S_p[32], S_nupd[32], S_rem[32];
  __shared__ int S_flag[1];          // alldone broadcast

  const int tid = threadIdx.x, bid = blockIdx.x;
  const int b_i = tid >> 3, sub = tid & 7;            // owner mapping
  const int b_g = tid & 31, s = tid >> 5;             // GEMM mapping
  const int wid = tid >> 6, lane = tid & 63;
  const int jown = bid * 4 + sub;                     // owner's j (sub<4)
  const int hoidx = bid * 128 + b_i * 4 + sub;
  const float4* hch4 = (const float4*)hch;
  const float4* Wq = (const float4*)W_halt;

  unsigned* flags = bar;             // flags[128]; group w = flags[32w..32w+32)
  const float bh = b_halt[0];

  // owner constants: flag column + biases for its 4 gates
  float wf0 = 0.f, wf1 = 0.f, wf2 = 0.f, wf3 = 0.f;
  float bs0 = 0.f, bs1 = 0.f, bs2 = 0.f, bs3 = 0.f;
  if (sub < 4) {
    const float4 wf = *(const float4*)(W_iT + 50 * 2048 + jown * 4);
    wf0 = wf.x; wf1 = wf.y; wf2 = wf.z; wf3 = wf.w;
    bs0 = bvec[jown]; bs1 = bvec[512 + jown]; bs2 = bvec[1024 + jown]; bs3 = bvec[1536 + jown];
  }

  // owner state
  float cS = 0.f, hprev = 0.f, acc_h = 0.f, acc_c = 0.f;
  float gA0 = 0.f, gA1 = 0.f, gA2 = 0.f, gA3 = 0.f;           // gAcc (linearity)
  float gc0 = 0.f, gc1 = 0.f, gc2 = 0.f, gc3 = 0.f;           // gx(t)
  float gn0 = 0.f, gn1 = 0.f, gn2 = 0.f, gn3 = 0.f;           // gx(t+1)
  if (sub < 4) {  // x-projection for t=0
    gc0 = bs0; gc1 = bs1; gc2 = bs2; gc3 = bs3;
    const float* xr = x + (size_t)b_i * 512 * 50;
    for (int k = 0; k < 50; ++k) {
      const float xv = xr[k];
      const float4 w = *(const float4*)(W_iT + k * 2048 + jown * 4);
      gc0 = fmaf(xv, w.x, gc0); gc1 = fmaf(xv, w.y, gc1);
      gc2 = fmaf(xv, w.z, gc2); gc3 = fmaf(xv, w.w, gc3);
    }
  }
  if (tid < 32) { S_cum[tid] = 0.f; S_nupd[tid] = 0.f; S_rem[tid] = 0.f; }
  int mydone = 0;
  int t = 0, n = 0, first = 1;
  unsigned ph = 0;
  __syncthreads();

  while (true) {
    if (first) {
      // ---- phase 0: step 0 of t=0 (h=0 -> gemm contribution = 0) ----
      if (sub < 4) {
        const float c_new = sigmf(gc0 + wf0) * tanhf(gc2 + wf2);
        const float h_new = sigmf(gc3 + wf3) * tanhf(c_new);
        store_llc(&hbuf[hoidx], h_new);
        cS = c_new; hprev = h_new;
      }
      n = 0; first = 0;
    } else {
      // ---- per-wave poll: only this wave's 32 producers (1-2 LLC lines) ----
      {
        const unsigned* fp = flags + wid * 32 + (lane & 31);
        while (true) {
          unsigned fv;
          asm volatile("global_load_dword %0, %1, off sc0 sc1" : "=v"(fv) : "v"(fp) : "memory");
          asm volatile("s_waitcnt vmcnt(0)" ::: "memory");
          if (__ballot(fv >= ph) == ~0ull) break;
        }
      }
      // ---- stage own 16 KB region from buf[(ph-1)&1] ----
      const float* hin = hbuf + ((ph & 1u) ^ 1u) * 16384;
      {
        const float* gp = hin + wid * 4096 + lane * 4;
        float* lp = &hch[wid * 4096];
        #pragma unroll
        for (int q = 0; q < 16; ++q) stage_instr(gp + q * 256, lp + q * 256);
      }
      // under the DMA: x-projection for t+1 (once per timestep)
      if (n == 0 && sub < 4) {
        const int tn = (t + 1 > 511) ? 511 : t + 1;
        gn0 = bs0; gn1 = bs1; gn2 = bs2; gn3 = bs3;
        const float* xr = x + ((size_t)b_i * 512 + tn) * 50;
        for (int k = 0; k < 50; ++k) {
          const float xv = xr[k];
          const float4 w = *(const float4*)(W_iT + k * 2048 + jown * 4);
          gn0 = fmaf(xv, w.x, gn0); gn1 = fmaf(xv, w.y, gn1);
          gn2 = fmaf(xv, w.z, gn2); gn3 = fmaf(xv, w.w, gn3);
        }
      }
      asm volatile("s_waitcnt vmcnt(0)" ::: "memory");  // own DMA done; no barrier

      // ---- k-sliced GEMM on OWN slices: 16 cols x 64 k per thread ----
      {
        float acc[16];
        #pragma unroll
        for (int q = 0; q < 16; ++q) acc[q] = 0.f;
        const float* hsl = hch + (s * 16) * 128 + b_g * 4;
        const float* wbase = W_ks + (size_t)bid * 8192 + s * 1024;  // contiguous 4KB/slice
        #pragma unroll 4
        for (int i = 0; i < 16; ++i) {
          const float4 h4 = *(const float4*)(hsl + i * 128);
          const float* wk = wbase + i * 64;
          #pragma unroll
          for (int kl = 0; kl < 4; ++kl) {
            const float hv = (kl == 0) ? h4.x : (kl == 1) ? h4.y : (kl == 2) ? h4.z : h4.w;
            const float4 w0 = *(const float4*)(wk + kl * 16);
            const float4 w1 = *(const float4*)(wk + kl * 16 + 4);
            const float4 w2 = *(const float4*)(wk + kl * 16 + 8);
            const float4 w3 = *(const float4*)(wk + kl * 16 + 12);
            acc[0]  = fmaf(hv, w0.x, acc[0]);  acc[1]  = fmaf(hv, w0.y, acc[1]);
            acc[2]  = fmaf(hv, w0.z, acc[2]);  acc[3]  = fmaf(hv, w0.w, acc[3]);
            acc[4]  = fmaf(hv, w1.x, acc[4]);  acc[5]  = fmaf(hv, w1.y, acc[5]);
            acc[6]  = fmaf(hv, w1.z, acc[6]);  acc[7]  = fmaf(hv, w1.w, acc[7]);
            acc[8]  = fmaf(hv, w2.x, acc[8]);  acc[9]  = fmaf(hv, w2.y, acc[9]);
            acc[10] = fmaf(hv, w2.z, acc[10]); acc[11] = fmaf(hv, w2.w, acc[11]);
            acc[12] = fmaf(hv, w3.x, acc[12]); acc[13] = fmaf(hv, w3.y, acc[13]);
            acc[14] = fmaf(hv, w3.z, acc[14]); acc[15] = fmaf(hv, w3.w, acc[15]);
          }
        }
        #pragma unroll
        for (int c = 0; c < 16; ++c) pacc[c * 292 + s * 36 + b_g] = acc[c];
      }
      // ---- halt partials on OWN staged region: f = wid*1024 + i*64 + lane ----
      {
        float hp = 0.f;
        #pragma unroll
        for (int i = 0; i < 16; ++i) {
          const int f = wid * 1024 + i * 64 + lane;
          const float4 hv = hch4[f];
          const float4 wv = Wq[f >> 5];
          hp = fmaf(hv.x, wv.x, fmaf(hv.y, wv.y, fmaf(hv.z, wv.z, fmaf(hv.w, wv.w, hp))));
        }
        hps[tid] = hp;   // partial for batch lane&31
      }
      __syncthreads();   // sync_c: all waves' pacc/hps ready

      // ---- reduction (all threads) + ACT decision (wave 0) ----
      {
        #pragma unroll
        for (int e = 0; e < 2; ++e) {
          const int f = tid + e * 256;
          const int b = f >> 4, c = f & 15;
          const float* pp = pacc + c * 292 + b;
          float v = 0.f;
          #pragma unroll
          for (int s2 = 0; s2 < 8; ++s2) v += pp[s2 * 36];
          xch2[f] = v;
        }
      }
      if (tid < 64) {
        int vote = 1;
        if (tid < 32) {
          float d = 0.f;
          #pragma unroll
          for (int r = 0; r < 8; ++r) d += hps[tid + 32 * r];
          const float halt = sigmf(d + bh);
          const float cum = S_cum[tid];
          const int done = mydone;
          const int halted = ((cum + halt) > 0.99f) || (n == 9);
          S_p[tid] = done ? 0.f : (halted ? (1.f - cum) : halt);
          S_nupd[tid] += done ? 0.f : 1.f;
          S_rem[tid] += (done || !halted) ? 0.f : (1.f - cum);
          S_cum[tid] = cum + (done ? 0.f : halt);
          mydone = done | halted;
          vote = mydone;
        }
        const unsigned long long bal = __ballot(vote);
        if (tid == 0) S_flag[0] = (bal == ~0ull) ? 1 : 0;
      }
      __syncthreads();   // sync_d
      const int alldone = S_flag[0];

      // ---- owner combine: accumulate + one cell step ----
      float g0 = 0.f, g1 = 0.f, g2 = 0.f, g3 = 0.f, p = 0.f;
      if (sub < 4) {
        const int bb = b_i * 16 + sub;
        g0 = xch2[bb]; g1 = xch2[bb + 4]; g2 = xch2[bb + 8]; g3 = xch2[bb + 12];
        p = S_p[b_i];
        gA0 = fmaf(p, g0, gA0); gA1 = fmaf(p, g1, gA1);
        gA2 = fmaf(p, g2, gA2); gA3 = fmaf(p, g3, gA3);
        acc_h = fmaf(p, hprev, acc_h);
        acc_c = fmaf(p, cS, acc_c);
      }

      if (alldone) {  // timestep t ends; fresh step of t+1 in the same phase
        if (sub < 4)
          wh[(size_t)t * 16384 + (size_t)b_i * 512 + jown] = acc_h;
        if (bid == 0 && tid < 32)
          p_out[(size_t)tid * 512 + t] = S_nupd[tid] + S_rem[tid];
        if (tid < 32) { S_cum[tid] = 0.f; S_nupd[tid] = 0.f; S_rem[tid] = 0.f; }
        mydone = 0;
        t += 1; n = 0;
        if (t == 512) break;        // uniform (deterministic replicated decisions)
        if (sub < 4) {              // fresh gates = gx(t+1) + wf + gAcc (no GEMM)
          const float c_new = sigmf(gn1 + wf1 + gA1) * acc_c +
                              sigmf(gn0 + wf0 + gA0) * tanhf(gn2 + wf2 + gA2);
          const float h_new = sigmf(gn3 + wf3 + gA3) * tanhf(c_new);
          store_llc(&hbuf[(ph & 1u) * 16384 + hoidx], h_new);
          cS = c_new; hprev = h_new;
          acc_h = 0.f; acc_c = 0.f;
          gA0 = 0.f; gA1 = 0.f; gA2 = 0.f; gA3 = 0.f;
          gc0 = gn0; gc1 = gn1; gc2 = gn2; gc3 = gn3;
        }
      } else {        // continue: step n+1 gates = gx(t) + gemm
        if (sub < 4) {
          const float c_new = sigmf(gc1 + g1) * cS + sigmf(gc0 + g0) * tanhf(gc2 + g2);
          const float h_new = sigmf(gc3 + g3) * tanhf(c_new);
          store_llc(&hbuf[(ph & 1u) * 16384 + hoidx], h_new);
          cS = c_new; hprev = h_new;
        }
        n += 1;
      }
    }

    // ---- publish: per-wave drain of h2 stores, sync, then flag store ----
    asm volatile("s_waitcnt vmcnt(0)" ::: "memory");
    __syncthreads();   // sync_e: all waves' stores at LLC
    if (tid == 0) store_llc_u(&flags[bid], ph + 1u);
    ph += 1;
  }
}

// ------------------------------------------------------------------
// epilogue: out[b,t,:] = seg-softmax(wh[t,b,:] @ W_out^T + b_out)
__global__ void __launch_bounds__(256)
epi_k(const float* __restrict__ wh, const float* __restrict__ W_oT,
      const float* __restrict__ b_out, float* __restrict__ out) {
  __shared__ float hl[4][512];
  __shared__ float yl[4][66];
  const int tid = threadIdx.x, pair = tid >> 6, lane = tid & 63;
  const int bt = blockIdx.x * 4 + pair;
  const int b = bt >> 9, t = bt & 511;
  const float* hsrc = wh + (size_t)t * 16384 + (size_t)b * 512;
  *(float4*)&hl[pair][lane * 8] = *(const float4*)(hsrc + lane * 8);
  *(float4*)&hl[pair][lane * 8 + 4] = *(const float4*)(hsrc + lane * 8 + 4);
  __syncthreads();
  if (lane < 33) {
    const int o = lane * 2;
    float y0 = b_out[o], y1 = b_out[o + 1];
    const float* hp_ = hl[pair];
    #pragma unroll 8
    for (int k = 0; k < 512; ++k) {
      const float h = hp_[k];
      const float2 w = *(const float2*)(W_oT + k * 66 + o);
      y0 = fmaf(h, w.x, y0);
      y1 = fmaf(h, w.y, y1);
    }
    yl[pair][o] = y0; yl[pair][o + 1] = y1;
  }
  __syncthreads();
  if (tid < 24) {
    const int pr = tid / 6, g = tid - pr * 6;
    const int bt2 = blockIdx.x * 4 + pr;
    const float* yp = &yl[pr][g * 11];
    float m = yp[0];
    for (int u = 1; u < 11; ++u) m = fmaxf(m, yp[u]);
    float e[11], ssum = 0.f;
    for (int u = 0; u < 11; ++u) { e[u] = expf(yp[u] - m); ssum += e[u]; }
    const float inv = 1.0f / ssum;
    float* op = out + (size_t)bt2 * 66 + g * 11;
    for (int u = 0; u < 11; ++u) op[u] = e[u] * inv;
  }
}

// ------------------------------------------------------------------
extern "C" void kernel_launch(void* const* d_in, const int* in_sizes, int n_in,
                              void* d_out, int out_size, void* d_ws, size_t ws_size,
                              hipStream_t stream) {
  (void)in_sizes; (void)n_in; (void)out_size;
  const float* x      = (const float*)d_in[0];
  const float* W_ih   = (const float*)d_in[1];
  const float* W_hh   = (const float*)d_in[2];
  const float* bvec   = (const float*)d_in[3];
  const float* W_out  = (const float*)d_in[4];
  const float* b_out  = (const float*)d_in[5];
  const float* W_halt = (const float*)d_in[6];
  const float* b_halt = (const float*)d_in[7];
  float* out = (float*)d_out;
  float* ws  = (float*)d_ws;

  if (ws_size < (size_t)WS_NEED_BYTES) return;  // visible failure if ws too small

  float* wh     = ws;
  float* hbuf   = ws + 8388608;
  unsigned* bar = (unsigned*)(ws + 8421376);
  float* W_ks   = ws + 8421888;
  float* W_iT   = ws + 9470464;
  float* W_oT   = ws + 9574912;
  float* p_out  = out + 1081344;  // B*T*OUT

  hipLaunchKernelGGL(prep_k, dim3(4638), dim3(256), 0, stream,
                     W_ih, W_hh, W_out, W_ks, W_iT, W_oT, bar);

  void* args[10];
  args[0] = (void*)&x;      args[1] = (void*)&bvec;  args[2] = (void*)&W_halt;
  args[3] = (void*)&b_halt; args[4] = (void*)&W_ks;  args[5] = (void*)&W_iT;
  args[6] = (void*)&hbuf;   args[7] = (void*)&bar;   args[8] = (void*)&wh;
  args[9] = (void*)&p_out;
  hipLaunchCooperativeKernel((void*)act_main, dim3(NBLK), dim3(256), args, 0, stream);

  hipLaunchKernelGGL(epi_k, dim3(4096), dim3(256), 0, stream, wh, W_oT, b_out, out);
}

// Round 11
// 11532.438 us; speedup vs baseline: 1.4758x; 1.2564x over previous
//
#include <hip/hip_runtime.h>
#include <stdint.h>
#include <stddef.h>

// ACT-LSTM, B=32 T=512 IN=50 H=512 OUT=66, MAX_PONDER=10, EPS=0.01, fp32.
// Round 11: round-10 batch-parallel design with the compile fix.
// 8 independent groups x 32 blocks (256 blocks, 1/CU). Group G owns batches
// [4G,4G+4) with a private timeline -- NO global sync. Per phase: one step for
// 4 batches (4x2048x512 GEMV). Block r owns 16 j (all 4 gates = 64 cols).
// h-exchange = 8 KB/group at the MALL (sc0 sc1); each WAVE polls just its 8
// producer flags and stages its own 2 KB k-slice -> wave-local pipeline.
// gAcc linearity trick retained (fresh step needs no GEMM).
// Fix vs R10: owner h2 publish = per-lane scalar sc0sc1 store (contiguous
// across the 64 owner lanes = coalesced 256B) -- no dwordx4 asm, no LDS hop.

#define NBLK 256

// ---------------- ws layout (float offsets) ----------------
// wh   : [0, 8388608)            512*32*512  (32 MB)
// hbuf : [8388608, 8421376)      8 groups x 2 pp x 2048  ([k][4b] packing)
// bar  : [8421376, 8421888)      flags[256] (group G = [32G,32G+32))
// Wp   : [8421888, 9470464)      W_hh repacked [r][k4][c][kl]  (4 MB)
// W_iT : [9470464, 9574912)      51*2048     W_ih repacked [k][j*4+g]
// W_oT : [9574912, 9608704)      512*66      W_out transposed [k][o]
#define WS_NEED_BYTES 38434816ull

__device__ __forceinline__ float sigmf(float v) { return 1.0f / (1.0f + expf(-v)); }

// LLC-coherent (cross-XCD) stores: bypass L1+L2 (sc0 sc1).
__device__ __forceinline__ void store_llc(float* p, float v) {
  asm volatile("global_store_dword %0, %1, off sc0 sc1" :: "v"(p), "v"(v) : "memory");
}
__device__ __forceinline__ void store_llc_u(unsigned* p, unsigned v) {
  asm volatile("global_store_dword %0, %1, off sc0 sc1" :: "v"(p), "v"(v) : "memory");
}

#if defined(__has_builtin)
#if __has_builtin(__builtin_amdgcn_global_load_lds)
#define HAVE_GLLDS 1
#endif
#endif

// LLC-coherent global->LDS DMA, 16 B/lane. aux=0x11 = SC0|SC1.
__device__ __forceinline__ void stage_instr(const float* gp, float* lp) {
#ifdef HAVE_GLLDS
  __builtin_amdgcn_global_load_lds((const __attribute__((address_space(1))) unsigned int*)gp,
                                   (__attribute__((address_space(3))) unsigned int*)lp,
                                   16, 0, 0x11);
#else
  float4 tmp;
  asm volatile("global_load_dwordx4 %0, %1, off sc0 sc1" : "=v"(tmp) : "v"(gp) : "memory");
  asm volatile("s_waitcnt vmcnt(0)" ::: "memory");
  *(float4*)(lp + (threadIdx.x & 63) * 4) = tmp;
#endif
}

// ------------------------------------------------------------------
// prep: repack weights + zero flags.
// Wp[((r*128+k4)*64+c)*4+kl] = W_hh[((c&3)*512 + 16r + (c>>2))*512 + 4k4+kl]
__global__ void prep_k(const float* __restrict__ W_ih, const float* __restrict__ W_hh,
                       const float* __restrict__ W_out,
                       float* __restrict__ Wp, float* __restrict__ W_iT,
                       float* __restrict__ W_oT, unsigned* __restrict__ bar) {
  int idx = blockIdx.x * 256 + threadIdx.x;
  if (idx < 1048576) {
    int kl = idx & 3, c = (idx >> 2) & 63, k4 = (idx >> 8) & 127, r = idx >> 15;
    int row = (c & 3) * 512 + 16 * r + (c >> 2);
    Wp[idx] = W_hh[(size_t)row * 512 + 4 * k4 + kl];
  }
  int i2 = idx - 1048576;
  if (i2 >= 0 && i2 < 104448) {
    int col = i2 & 2047, k = i2 >> 11;
    int g = col & 3, j = col >> 2;
    W_iT[i2] = W_ih[(size_t)((g << 9) + j) * 51 + k];
  }
  int i3 = idx - 1153024;
  if (i3 >= 0 && i3 < 33792) {
    int k = i3 / 66, o = i3 - k * 66;
    W_oT[i3] = W_out[(size_t)o * 512 + k];
  }
  int i4 = idx - 1186816;
  if (i4 >= 0 && i4 < 256) bar[i4] = 0u;
}

// ------------------------------------------------------------------
// persistent ACT-LSTM: 256 blocks x 256 threads; group gid=bid>>5 (batches
// 4gid..4gid+3), rank r=bid&31 owns j in [16r,16r+16).
// (c,b)-role: c=tid&63 (col: g=c&3, jj=c>>2), batch=w=tid>>6. GEMV: thread
// computes col c x 4 batches over k-slice [128w,128w+128).
// Owner lane (tid<64): jj=tid>>2, bo=tid&3 owns (batch 4gid+bo, j=16r+jj);
// its h2 slot is hbG + pp*2048 + 64r + tid (contiguous across lanes).
// Decision lanes tid<4 (batch=tid).
__global__ void __launch_bounds__(256)
act_main(const float* __restrict__ x, const float* __restrict__ bvec,
         const float* __restrict__ W_halt, const float* __restrict__ b_halt,
         const float* __restrict__ Wp, const float* __restrict__ W_iT,
         float* __restrict__ hbuf, unsigned* __restrict__ bar,
         float* __restrict__ wh, float* __restrict__ p_out) {
  __shared__ float hst[2048];        // staged h [k][4b], 8 KB (wave-private 2KB regions)
  __shared__ float pacc[1024];       // GEMV partials [s][c][4b]
  __shared__ float xg2[256];         // final gate pre-acts [c][4b]
  __shared__ float hps[256];         // halt partials
  __shared__ float S_p[4];
  __shared__ int S_flag[1];

  const int tid = threadIdx.x, bid = blockIdx.x;
  const int gid = bid >> 5, r = bid & 31;
  const int c = tid & 63, w = tid >> 6, lane = tid & 63;
  const int jj = tid >> 2, bo = tid & 3;          // owner mapping (tid<64)
  const int ch = lane >> 2, b2 = lane & 3;        // halt-partial mapping
  unsigned* flags = bar + gid * 32;
  float* hbG = hbuf + gid * 4096;

  const float bh = b_halt[0];
  const int cg = 64 * r + c;                       // W_iT column for (r,c)
  const float bs = bvec[(c & 3) * 512 + 16 * r + (c >> 2)];
  const float wfc = W_iT[50 * 2048 + cg];

  // (c,batch=w) state
  float gAcc = 0.f, gxc, gxn = 0.f;
  {  // x-projection for t=0, batch 4gid+w
    gxc = bs;
    const float* xr = x + (size_t)(gid * 4 + w) * 512 * 50;
    for (int k = 0; k < 50; ++k) gxc = fmaf(xr[k], W_iT[k * 2048 + cg], gxc);
  }
  // owner state (tid<64)
  float cS = 0.f, hprev = 0.f, acc_h = 0.f, acc_c = 0.f;
  // decision state (tid<4)
  float cum = 0.f, nupd = 0.f, rem = 0.f;
  int mydone = 0;

  int t = 0, n = 0, first = 1;
  unsigned ph = 0;
  __syncthreads();

  while (true) {
    float val, cin = 0.f;
    if (first) {
      // phase 0: fresh step (t=0,n=0), h=0 -> gemm=0, gAcc=0
      val = gxc + wfc;
      first = 0;
    } else {
      // ---- per-wave poll: the 8 producers of this wave's k-slice ----
      {
        const unsigned* fp = flags + w * 8 + (lane & 7);
        while (true) {
          unsigned fv;
          asm volatile("global_load_dword %0, %1, off sc0 sc1" : "=v"(fv) : "v"(fp) : "memory");
          asm volatile("s_waitcnt vmcnt(0)" ::: "memory");
          if (__ballot((lane < 8) ? (fv >= ph) : 1) == ~0ull) break;
          __builtin_amdgcn_s_sleep(1);
        }
      }
      // ---- stage own 2 KB (k in [128w,+128), [k][4b]) ----
      {
        const float* gp = hbG + ((ph & 1u) ^ 1u) * 2048 + w * 512 + lane * 4;
        float* lp = hst + w * 512;
        stage_instr(gp, lp); stage_instr(gp + 256, lp + 256);
      }
      // under the DMA: x-projection for t+1 (once per timestep)
      if (n == 0) {
        const int tn = (t + 1 > 511) ? 511 : t + 1;
        gxn = bs;
        const float* xr = x + ((size_t)(gid * 4 + w) * 512 + tn) * 50;
        for (int k = 0; k < 50; ++k) gxn = fmaf(xr[k], W_iT[k * 2048 + cg], gxn);
      }
      asm volatile("s_waitcnt vmcnt(0)" ::: "memory");

      // ---- GEMV slice: col c, 4 batches, k in [128w,+128) ----
      {
        const float* wb = Wp + (size_t)r * 32768 + w * 8192 + c * 4;
        const float* hb = hst + w * 512;
        float a0 = 0.f, a1 = 0.f, a2 = 0.f, a3 = 0.f;
        #pragma unroll 8
        for (int i = 0; i < 32; ++i) {
          const float4 wv = *(const float4*)(wb + i * 256);   // 1 KB/wave, coalesced
          const float4 h0 = *(const float4*)(hb + i * 16);    // wave-uniform broadcast
          const float4 h1 = *(const float4*)(hb + i * 16 + 4);
          const float4 h2v = *(const float4*)(hb + i * 16 + 8);
          const float4 h3 = *(const float4*)(hb + i * 16 + 12);
          a0 = fmaf(wv.x, h0.x, a0); a1 = fmaf(wv.x, h0.y, a1);
          a2 = fmaf(wv.x, h0.z, a2); a3 = fmaf(wv.x, h0.w, a3);
          a0 = fmaf(wv.y, h1.x, a0); a1 = fmaf(wv.y, h1.y, a1);
          a2 = fmaf(wv.y, h1.z, a2); a3 = fmaf(wv.y, h1.w, a3);
          a0 = fmaf(wv.z, h2v.x, a0); a1 = fmaf(wv.z, h2v.y, a1);
          a2 = fmaf(wv.z, h2v.z, a2); a3 = fmaf(wv.z, h2v.w, a3);
          a0 = fmaf(wv.w, h3.x, a0); a1 = fmaf(wv.w, h3.y, a1);
          a2 = fmaf(wv.w, h3.z, a2); a3 = fmaf(wv.w, h3.w, a3);
        }
        float4 pv; pv.x = a0; pv.y = a1; pv.z = a2; pv.w = a3;
        *(float4*)(pacc + w * 256 + c * 4) = pv;   // lanes contiguous
      }
      // ---- halt partial on own slice: k = 128w + ch + 16i ----
      {
        float hp = 0.f;
        #pragma unroll
        for (int i = 0; i < 8; ++i) {
          const int k = 128 * w + ch + 16 * i;
          hp = fmaf(hst[k * 4 + b2], W_halt[k], hp);
        }
        hps[tid] = hp;     // partial for batch lane&3
      }
      __syncthreads();   // sync_c

      // (c,w): reduce own gate over the 4 k-slices
      const float g = pacc[c * 4 + w] + pacc[256 + c * 4 + w] +
                      pacc[512 + c * 4 + w] + pacc[768 + c * 4 + w];
      // wave 0: ACT decision for the 4 batches
      if (tid < 64) {
        int vote = 1;
        if (tid < 4) {
          float d = 0.f;
          for (int m = 0; m < 64; ++m) d += hps[m * 4 + tid];
          const float halt = sigmf(d + bh);
          const int done = mydone;
          const int halted = ((cum + halt) > 0.99f) || (n == 9);
          S_p[tid] = done ? 0.f : (halted ? (1.f - cum) : halt);
          nupd += done ? 0.f : 1.f;
          rem += (done || !halted) ? 0.f : (1.f - cum);
          cum += done ? 0.f : halt;
          mydone = done | halted;
          vote = mydone;
        }
        const unsigned long long bal = __ballot(vote);
        if (tid == 0) S_flag[0] = (bal == ~0ull) ? 1 : 0;
      }
      __syncthreads();   // sync_d

      const int alldone = S_flag[0];
      const float p = S_p[w];
      gAcc = fmaf(p, g, gAcc);
      if (tid < 64) {    // owner accumulate (weighted h,c of staged step)
        const float po = S_p[bo];
        acc_h = fmaf(po, hprev, acc_h);
        acc_c = fmaf(po, cS, acc_c);
      }
      if (alldone) {     // timestep t ends; fresh step of t+1 this phase
        if (tid < 64) {
          wh[(size_t)t * 16384 + (size_t)(gid * 4 + bo) * 512 + 16 * r + jj] = acc_h;
          cin = acc_c;
          acc_h = 0.f; acc_c = 0.f;
        }
        if (r == 0 && tid < 4)
          p_out[(size_t)(gid * 4 + tid) * 512 + t] = nupd + rem;
        if (tid < 4) { cum = 0.f; nupd = 0.f; rem = 0.f; mydone = 0; }
        val = gxn + wfc + gAcc;      // fresh gates: no GEMM (linearity)
        gAcc = 0.f; gxc = gxn;
        t += 1; n = 0;
        if (t == 512) break;         // uniform within block & group
      } else {
        if (tid < 64) cin = cS;
        val = gxc + g;
        n += 1;
      }
    }

    xg2[c * 4 + w] = val;
    __syncthreads();   // sync_e
    if (tid < 64) {    // owner (jj,bo): cell step; publish h2 (coalesced); flag
      const float gi = xg2[16 * jj + 0 + bo];
      const float gf = xg2[16 * jj + 4 + bo];
      const float gg = xg2[16 * jj + 8 + bo];
      const float go = xg2[16 * jj + 12 + bo];
      const float c_new = sigmf(gf) * cin + sigmf(gi) * tanhf(gg);
      const float h_new = sigmf(go) * tanhf(c_new);
      cS = c_new; hprev = h_new;
      store_llc(hbG + (ph & 1u) * 2048 + 64 * r + tid, h_new);
      asm volatile("s_waitcnt vmcnt(0)" ::: "memory");
      if (tid == 0) store_llc_u(&flags[r], ph + 1u);
    }
    ph += 1;
  }
}

// ------------------------------------------------------------------
// epilogue: out[b,t,:] = seg-softmax(wh[t,b,:] @ W_out^T + b_out)
__global__ void __launch_bounds__(256)
epi_k(const float* __restrict__ wh, const float* __restrict__ W_oT,
      const float* __restrict__ b_out, float* __restrict__ out) {
  __shared__ float hl[4][512];
  __shared__ float yl[4][66];
  const int tid = threadIdx.x, pair = tid >> 6, lane = tid & 63;
  const int bt = blockIdx.x * 4 + pair;
  const int b = bt >> 9, t = bt & 511;
  const float* hsrc = wh + (size_t)t * 16384 + (size_t)b * 512;
  *(float4*)&hl[pair][lane * 8] = *(const float4*)(hsrc + lane * 8);
  *(float4*)&hl[pair][lane * 8 + 4] = *(const float4*)(hsrc + lane * 8 + 4);
  __syncthreads();
  if (lane < 33) {
    const int o = lane * 2;
    float y0 = b_out[o], y1 = b_out[o + 1];
    const float* hp_ = hl[pair];
    #pragma unroll 8
    for (int k = 0; k < 512; ++k) {
      const float h = hp_[k];
      const float2 wv = *(const float2*)(W_oT + k * 66 + o);
      y0 = fmaf(h, wv.x, y0);
      y1 = fmaf(h, wv.y, y1);
    }
    yl[pair][o] = y0; yl[pair][o + 1] = y1;
  }
  __syncthreads();
  if (tid < 24) {
    const int pr = tid / 6, g = tid - pr * 6;
    const int bt2 = blockIdx.x * 4 + pr;
    const float* yp = &yl[pr][g * 11];
    float m = yp[0];
    for (int u = 1; u < 11; ++u) m = fmaxf(m, yp[u]);
    float e[11], ssum = 0.f;
    for (int u = 0; u < 11; ++u) { e[u] = expf(yp[u] - m); ssum += e[u]; }
    const float inv = 1.0f / ssum;
    float* op = out + (size_t)bt2 * 66 + g * 11;
    for (int u = 0; u < 11; ++u) op[u] = e[u] * inv;
  }
}

// ------------------------------------------------------------------
extern "C" void kernel_launch(void* const* d_in, const int* in_sizes, int n_in,
                              void* d_out, int out_size, void* d_ws, size_t ws_size,
                              hipStream_t stream) {
  (void)in_sizes; (void)n_in; (void)out_size;
  const float* x      = (const float*)d_in[0];
  const float* W_ih   = (const float*)d_in[1];
  const float* W_hh   = (const float*)d_in[2];
  const float* bvec   = (const float*)d_in[3];
  const float* W_out  = (const float*)d_in[4];
  const float* b_out  = (const float*)d_in[5];
  const float* W_halt = (const float*)d_in[6];
  const float* b_halt = (const float*)d_in[7];
  float* out = (float*)d_out;
  float* ws  = (float*)d_ws;

  if (ws_size < (size_t)WS_NEED_BYTES) return;  // visible failure if ws too small

  float* wh     = ws;
  float* hbuf   = ws + 8388608;
  unsigned* bar = (unsigned*)(ws + 8421376);
  float* Wp     = ws + 8421888;
  float* W_iT   = ws + 9470464;
  float* W_oT   = ws + 9574912;
  float* p_out  = out + 1081344;  // B*T*OUT

  hipLaunchKernelGGL(prep_k, dim3(4638), dim3(256), 0, stream,
                     W_ih, W_hh, W_out, Wp, W_iT, W_oT, bar);

  void* args[10];
  args[0] = (void*)&x;      args[1] = (void*)&bvec;  args[2] = (void*)&W_halt;
  args[3] = (void*)&b_halt; args[4] = (void*)&Wp;    args[5] = (void*)&W_iT;
  args[6] = (void*)&hbuf;   args[7] = (void*)&bar;   args[8] = (void*)&wh;
  args[9] = (void*)&p_out;
  (void)hipLaunchCooperativeKernel((void*)act_main, dim3(NBLK), dim3(256), args, 0, stream);

  hipLaunchKernelGGL(epi_k, dim3(4096), dim3(256), 0, stream, wh, W_oT, b_out, out);
}